// Round 1
// baseline (600.062 us; speedup 1.0000x reference)
//
#include <hip/hip_runtime.h>
#include <hip/hip_bf16.h>

// Problem constants: D=256, NQ=512, NK=512, 2D=512.
#define DD 256
#define NN 512

// ---------------------------------------------------------------------------
// Generic "rows" GEMM: out[r][n] = act( sum_c A[r][c]*B[c][n] + bias[r] )
// A row-major with row stride lda; B is [K][N] with n contiguous (coalesced
// across the 64 lanes of threadIdx.x); A reads are wave-uniform -> s_load.
// B is split into two buffers at `split` (for the concat [x; message]).
// block = (64, 4); each thread computes RPT consecutive rows.
// ---------------------------------------------------------------------------
template <int K, int RPT, bool RELU>
__global__ __launch_bounds__(256) void gemm_rows(
    const float* __restrict__ A, int lda,
    const float* __restrict__ B0, const float* __restrict__ B1, int split,
    const float* __restrict__ bias, float* __restrict__ out) {
  const int n = blockIdx.x * 64 + threadIdx.x;
  const int r0 = (blockIdx.y * 4 + threadIdx.y) * RPT;

  float acc[RPT];
#pragma unroll
  for (int i = 0; i < RPT; ++i) acc[i] = 0.0f;

  int c = 0;
  for (; c < split; ++c) {
    const float bv = B0[c * NN + n];
#pragma unroll
    for (int i = 0; i < RPT; ++i) acc[i] += A[(r0 + i) * lda + c] * bv;
  }
  for (; c < K; ++c) {
    const float bv = B1[(c - split) * NN + n];
#pragma unroll
    for (int i = 0; i < RPT; ++i) acc[i] += A[(r0 + i) * lda + c] * bv;
  }

#pragma unroll
  for (int i = 0; i < RPT; ++i) {
    float v = acc[i] + (bias ? bias[r0 + i] : 0.0f);
    if (RELU) v = fmaxf(v, 0.0f);
    out[(r0 + i) * NN + n] = v;
  }
}

// ---------------------------------------------------------------------------
// scores[n][m] = sum_d w2[d] * relu(aq[d][n] + ak[d][m]) + b2
// Block computes a 32x32 tile; d staged in LDS chunks of 128.
// tid = flat 0..255; tn = tid&31 (n lane), tm4 = (tid>>5)*4 (4 m's / thread).
// ---------------------------------------------------------------------------
__global__ __launch_bounds__(256) void scores_kernel(
    const float* __restrict__ aq, const float* __restrict__ ak,
    const float* __restrict__ w2, const float* __restrict__ b2,
    float* __restrict__ scores) {
  __shared__ float aqs[128][32];
  __shared__ float aks[128][32];
  __shared__ float w2s[DD];

  const int tid = threadIdx.x;
  const int n0 = blockIdx.x * 32;
  const int m0 = blockIdx.y * 32;
  const int tn = tid & 31;
  const int tm4 = (tid >> 5) * 4;

  w2s[tid] = w2[tid];  // tid 0..255 covers DD=256

  float s0 = 0.f, s1 = 0.f, s2 = 0.f, s3 = 0.f;

  for (int d0 = 0; d0 < DD; d0 += 128) {
    __syncthreads();
#pragma unroll
    for (int k = 0; k < 16; ++k) {  // 128*32 / 256 = 16 loads per thread
      const int idx = k * 256 + tid;
      const int r = idx >> 5, cc = idx & 31;
      aqs[r][cc] = aq[(d0 + r) * NN + n0 + cc];
      aks[r][cc] = ak[(d0 + r) * NN + m0 + cc];
    }
    __syncthreads();

    for (int dd = 0; dd < 128; ++dd) {
      const float w = w2s[d0 + dd];
      const float a = aqs[dd][tn];
      const float4 akv = *(const float4*)&aks[dd][tm4];
      s0 += w * fmaxf(a + akv.x, 0.0f);
      s1 += w * fmaxf(a + akv.y, 0.0f);
      s2 += w * fmaxf(a + akv.z, 0.0f);
      s3 += w * fmaxf(a + akv.w, 0.0f);
    }
  }

  const float bv = b2[0];
  float4 o;
  o.x = s0 + bv; o.y = s1 + bv; o.z = s2 + bv; o.w = s3 + bv;
  *(float4*)&scores[(n0 + tn) * NN + m0 + tm4] = o;
}

// ---------------------------------------------------------------------------
// Row softmax over m (512) — one block (256 threads) per row.
// ---------------------------------------------------------------------------
__global__ __launch_bounds__(256) void softmax_kernel(
    const float* __restrict__ scores, float* __restrict__ prob) {
  __shared__ float red[256];
  const int n = blockIdx.x;
  const int t = threadIdx.x;

  const float v0 = scores[n * NN + t];
  const float v1 = scores[n * NN + 256 + t];

  red[t] = fmaxf(v0, v1);
  __syncthreads();
  for (int s = 128; s > 0; s >>= 1) {
    if (t < s) red[t] = fmaxf(red[t], red[t + s]);
    __syncthreads();
  }
  const float mx = red[0];
  __syncthreads();

  const float e0 = __expf(v0 - mx);
  const float e1 = __expf(v1 - mx);
  red[t] = e0 + e1;
  __syncthreads();
  for (int s = 128; s > 0; s >>= 1) {
    if (t < s) red[t] += red[t + s];
    __syncthreads();
  }
  const float inv = 1.0f / red[0];

  prob[n * NN + t] = e0 * inv;
  prob[n * NN + 256 + t] = e1 * inv;
}

// ---------------------------------------------------------------------------
// 512x512 f32 transpose (prob -> probT), 32x32 LDS tiles (+1 pad).
// block (32,8), grid (16,16).
// ---------------------------------------------------------------------------
__global__ __launch_bounds__(256) void transpose_kernel(
    const float* __restrict__ in, float* __restrict__ out) {
  __shared__ float tile[32][33];
  const int x = blockIdx.x * 32 + threadIdx.x;
  const int y0 = blockIdx.y * 32;
#pragma unroll
  for (int i = threadIdx.y; i < 32; i += 8)
    tile[i][threadIdx.x] = in[(y0 + i) * NN + x];
  __syncthreads();
  const int ox = blockIdx.y * 32 + threadIdx.x;
  const int oy0 = blockIdx.x * 32;
#pragma unroll
  for (int i = threadIdx.y; i < 32; i += 8)
    out[(oy0 + i) * NN + ox] = tile[threadIdx.x][i];
}

// ---------------------------------------------------------------------------
extern "C" void kernel_launch(void* const* d_in, const int* in_sizes, int n_in,
                              void* d_out, int out_size, void* d_ws, size_t ws_size,
                              hipStream_t stream) {
  (void)in_sizes; (void)n_in; (void)out_size; (void)ws_size;

  const float* x   = (const float*)d_in[0];  // (256, 512)
  const float* src = (const float*)d_in[1];  // (256, 512)
  const float* w1  = (const float*)d_in[2];  // (256, 512)
  const float* b1  = (const float*)d_in[3];  // (256,)
  const float* w2  = (const float*)d_in[4];  // (1, 256)
  const float* b2  = (const float*)d_in[5];  // (1,)
  const float* wa  = (const float*)d_in[6];  // (512, 512)
  const float* ba  = (const float*)d_in[7];  // (512,)
  const float* wb  = (const float*)d_in[8];  // (256, 512)
  const float* bb  = (const float*)d_in[9];  // (256,)

  float* y_out   = (float*)d_out;            // (256, 512) = 131072
  float* sc_out  = (float*)d_out + 131072;   // (512, 512) = 262144

  float* ws = (float*)d_ws;
  float* aq    = ws;            // 131072
  float* ak    = ws + 131072;   // 131072
  float* prob  = ws + 262144;   // 262144
  float* probT = ws + 524288;   // 262144
  float* msg   = ws + 786432;   // 131072
  float* h2    = ws + 917504;   // 262144

  const dim3 gblk(64, 4);

  // aq = w1[:, :256] @ x + b1   (M=256, K=256)
  gemm_rows<256, 2, false><<<dim3(8, 32), gblk, 0, stream>>>(
      w1, 512, x, x, 256, b1, aq);
  // ak = w1[:, 256:] @ src      (M=256, K=256)
  gemm_rows<256, 2, false><<<dim3(8, 32), gblk, 0, stream>>>(
      w1 + 256, 512, src, src, 256, nullptr, ak);

  // scores (written straight to output region)
  scores_kernel<<<dim3(16, 16), dim3(256), 0, stream>>>(aq, ak, w2, b2, sc_out);

  // softmax over m
  softmax_kernel<<<dim3(512), dim3(256), 0, stream>>>(sc_out, prob);

  // probT[m][n] = prob[n][m]
  transpose_kernel<<<dim3(16, 16), dim3(32, 8), 0, stream>>>(prob, probT);

  // message[d][n] = sum_m src[d][m] * probT[m][n]   (M=256, K=512)
  gemm_rows<512, 2, false><<<dim3(8, 32), gblk, 0, stream>>>(
      src, 512, probT, probT, 512, nullptr, msg);

  // h2 = relu(wa @ [x; msg] + ba)   (M=512, K=512, split B)
  gemm_rows<512, 4, true><<<dim3(8, 32), gblk, 0, stream>>>(
      wa, 512, x, msg, 256, ba, h2);

  // y = wb @ h2 + bb                (M=256, K=512)
  gemm_rows<512, 2, false><<<dim3(8, 32), gblk, 0, stream>>>(
      wb, 512, h2, h2, 512, bb, y_out);
}

// Round 2
// 166.422 us; speedup vs baseline: 3.6057x; 3.6057x over previous
//
#include <hip/hip_runtime.h>
#include <hip/hip_bf16.h>

// Problem constants: D=256, NQ=NK=512.
#define DD 256
#define NN 512

// ---------------------------------------------------------------------------
// Tiled f32 GEMM core: out[m][n] = act( sum_k A[m][k]*B[k][n] + bias[m] )
// Tile: 32 (M) x 64 (N), BK = 32, 256 threads.
// Thread (tx = tid&15 -> 4 consecutive n, ty = tid>>4 -> rows ty and ty+16).
// TRANSB: B_eff[k][n] = B[n][k]  (stages prob with an LDS transpose).
// B2 != null: B := B0 + B1 during staging (consumes split-K partials).
// stage_relu: relu applied to staged B (consumes pre-activation h2 partials).
// ---------------------------------------------------------------------------
template <bool TRANSB>
__device__ __forceinline__ void gemm_tile(
    const float* __restrict__ A, int lda,
    const float* __restrict__ B, const float* __restrict__ B2, bool stage_relu,
    const float* __restrict__ bias, bool relu_out,
    float* __restrict__ out, int K, int m0, int n0) {
  __shared__ float As[32][33];   // [k][m], +1 pad
  __shared__ float Bs[32][68];   // [k][n], +4 pad keeps 16B alignment

  const int tid = threadIdx.x;
  const int tx = tid & 15;
  const int ty = tid >> 4;

  float acc0[4] = {0.f, 0.f, 0.f, 0.f};
  float acc1[4] = {0.f, 0.f, 0.f, 0.f};

  const int arow = tid >> 3;        // 0..31 (m within tile)
  const int akk  = (tid & 7) << 2;  // 0,4,...,28 (k within chunk)

  for (int k0 = 0; k0 < K; k0 += 32) {
    __syncthreads();
    // ---- stage A transposed: As[k][m]
    {
      const float4 av = *(const float4*)&A[(m0 + arow) * lda + k0 + akk];
      As[akk + 0][arow] = av.x;
      As[akk + 1][arow] = av.y;
      As[akk + 2][arow] = av.z;
      As[akk + 3][arow] = av.w;
    }
    // ---- stage B: Bs[k][n]
    if (TRANSB) {
#pragma unroll
      for (int t = tid; t < 512; t += 256) {
        const int ni = t >> 3;           // 0..63 (n within tile)
        const int k4 = (t & 7) << 2;     // 0,4,...,28
        const float4 v = *(const float4*)&B[(n0 + ni) * NN + k0 + k4];
        Bs[k4 + 0][ni] = v.x;
        Bs[k4 + 1][ni] = v.y;
        Bs[k4 + 2][ni] = v.z;
        Bs[k4 + 3][ni] = v.w;
      }
    } else {
#pragma unroll
      for (int t = tid; t < 512; t += 256) {
        const int row = t >> 4;          // 0..31 (k)
        const int c4  = (t & 15) << 2;   // 0,4,...,60 (n)
        float4 v = *(const float4*)&B[(k0 + row) * NN + n0 + c4];
        if (B2) {
          const float4 v2 = *(const float4*)&B2[(k0 + row) * NN + n0 + c4];
          v.x += v2.x; v.y += v2.y; v.z += v2.z; v.w += v2.w;
        }
        if (stage_relu) {
          v.x = fmaxf(v.x, 0.f); v.y = fmaxf(v.y, 0.f);
          v.z = fmaxf(v.z, 0.f); v.w = fmaxf(v.w, 0.f);
        }
        *(float4*)&Bs[row][c4] = v;
      }
    }
    __syncthreads();

    // ---- inner product over the chunk
#pragma unroll
    for (int k = 0; k < 32; ++k) {
      const float a0 = As[k][ty];
      const float a1 = As[k][ty + 16];
      const float4 b = *(const float4*)&Bs[k][tx << 2];
      acc0[0] += a0 * b.x; acc0[1] += a0 * b.y;
      acc0[2] += a0 * b.z; acc0[3] += a0 * b.w;
      acc1[0] += a1 * b.x; acc1[1] += a1 * b.y;
      acc1[2] += a1 * b.z; acc1[3] += a1 * b.w;
    }
  }

  // ---- epilogue
  const int m_a = m0 + ty;
  const int m_b = m0 + ty + 16;
  const float bv0 = bias ? bias[m_a] : 0.f;
  const float bv1 = bias ? bias[m_b] : 0.f;
  float4 o0, o1;
  o0.x = acc0[0] + bv0; o0.y = acc0[1] + bv0;
  o0.z = acc0[2] + bv0; o0.w = acc0[3] + bv0;
  o1.x = acc1[0] + bv1; o1.y = acc1[1] + bv1;
  o1.z = acc1[2] + bv1; o1.w = acc1[3] + bv1;
  if (relu_out) {
    o0.x = fmaxf(o0.x, 0.f); o0.y = fmaxf(o0.y, 0.f);
    o0.z = fmaxf(o0.z, 0.f); o0.w = fmaxf(o0.w, 0.f);
    o1.x = fmaxf(o1.x, 0.f); o1.y = fmaxf(o1.y, 0.f);
    o1.z = fmaxf(o1.z, 0.f); o1.w = fmaxf(o1.w, 0.f);
  }
  *(float4*)&out[m_a * NN + n0 + (tx << 2)] = o0;
  *(float4*)&out[m_b * NN + n0 + (tx << 2)] = o1;
}

// ---- aq = w1[:, :256] @ x + b1 ; ak = w1[:, 256:] @ src  (z selects)
__global__ __launch_bounds__(256) void aqak_kernel(
    const float* __restrict__ w1, const float* __restrict__ x,
    const float* __restrict__ src, const float* __restrict__ b1,
    float* __restrict__ aq, float* __restrict__ ak) {
  const float* A;
  const float* B;
  const float* bias;
  float* out;
  if (blockIdx.z == 0) { A = w1;       B = x;   bias = b1;      out = aq; }
  else                 { A = w1 + 256; B = src; bias = nullptr; out = ak; }
  gemm_tile<false>(A, 512, B, nullptr, false, bias, false, out,
                   256, blockIdx.y * 32, blockIdx.x * 64);
}

// ---- msg partials over m-halves: msgZ[d][n] = sum_{m in half} src[d][m]*prob[n][m]
__global__ __launch_bounds__(256) void msg_kernel(
    const float* __restrict__ src, const float* __restrict__ prob,
    float* __restrict__ msgA, float* __restrict__ msgB) {
  const int z = blockIdx.z;
  const float* A = src + z * 256;       // columns (m) offset
  const float* P = prob + z * 256;      // P[n][k], k = local m
  float* out = z ? msgB : msgA;
  gemm_tile<true>(A, 512, P, nullptr, false, nullptr, false, out,
                  256, blockIdx.y * 32, blockIdx.x * 64);
}

// ---- h2 partials (pre-relu): z=0: wa[:,:256]@x + ba ; z=1: wa[:,256:]@(msgA+msgB)
__global__ __launch_bounds__(256) void h2_kernel(
    const float* __restrict__ wa, const float* __restrict__ x,
    const float* __restrict__ msgA, const float* __restrict__ msgB,
    const float* __restrict__ ba, float* __restrict__ h2A,
    float* __restrict__ h2B) {
  const int z = blockIdx.z;
  const float* A  = z ? wa + 256 : wa;
  const float* B  = z ? msgA : x;
  const float* B2 = z ? msgB : nullptr;
  const float* bias = z ? nullptr : ba;
  float* out = z ? h2B : h2A;
  gemm_tile<false>(A, 512, B, B2, false, bias, false, out,
                   256, blockIdx.y * 32, blockIdx.x * 64);
}

// ---- y = wb @ relu(h2A + h2B) + bb   (relu fused into B staging)
__global__ __launch_bounds__(256) void y_kernel(
    const float* __restrict__ wb, const float* __restrict__ h2A,
    const float* __restrict__ h2B, const float* __restrict__ bb,
    float* __restrict__ y) {
  gemm_tile<false>(wb, 512, h2A, h2B, true, bb, false, y,
                   512, blockIdx.y * 32, blockIdx.x * 64);
}

// ---------------------------------------------------------------------------
// scores[n][m] = sum_d w2[d] * relu(aq[d][n] + ak[d][m]) + b2
// ---------------------------------------------------------------------------
__global__ __launch_bounds__(256) void scores_kernel(
    const float* __restrict__ aq, const float* __restrict__ ak,
    const float* __restrict__ w2, const float* __restrict__ b2,
    float* __restrict__ scores) {
  __shared__ float aqs[128][32];
  __shared__ float aks[128][32];
  __shared__ float w2s[DD];

  const int tid = threadIdx.x;
  const int n0 = blockIdx.x * 32;
  const int m0 = blockIdx.y * 32;
  const int tn = tid & 31;
  const int tm4 = (tid >> 5) * 4;

  w2s[tid] = w2[tid];

  float s0 = 0.f, s1 = 0.f, s2 = 0.f, s3 = 0.f;

  for (int d0 = 0; d0 < DD; d0 += 128) {
    __syncthreads();
#pragma unroll
    for (int k = 0; k < 16; ++k) {
      const int idx = k * 256 + tid;
      const int r = idx >> 5, cc = idx & 31;
      aqs[r][cc] = aq[(d0 + r) * NN + n0 + cc];
      aks[r][cc] = ak[(d0 + r) * NN + m0 + cc];
    }
    __syncthreads();

    for (int dd = 0; dd < 128; ++dd) {
      const float w = w2s[d0 + dd];
      const float a = aqs[dd][tn];
      const float4 akv = *(const float4*)&aks[dd][tm4];
      s0 += w * fmaxf(a + akv.x, 0.0f);
      s1 += w * fmaxf(a + akv.y, 0.0f);
      s2 += w * fmaxf(a + akv.z, 0.0f);
      s3 += w * fmaxf(a + akv.w, 0.0f);
    }
  }

  const float bv = b2[0];
  float4 o;
  o.x = s0 + bv; o.y = s1 + bv; o.z = s2 + bv; o.w = s3 + bv;
  *(float4*)&scores[(n0 + tn) * NN + m0 + tm4] = o;
}

// ---------------------------------------------------------------------------
// Row softmax over m (512) — one block (256 threads) per row n.
// ---------------------------------------------------------------------------
__global__ __launch_bounds__(256) void softmax_kernel(
    const float* __restrict__ scores, float* __restrict__ prob) {
  __shared__ float red[256];
  const int n = blockIdx.x;
  const int t = threadIdx.x;

  const float v0 = scores[n * NN + t];
  const float v1 = scores[n * NN + 256 + t];

  red[t] = fmaxf(v0, v1);
  __syncthreads();
  for (int s = 128; s > 0; s >>= 1) {
    if (t < s) red[t] = fmaxf(red[t], red[t + s]);
    __syncthreads();
  }
  const float mx = red[0];
  __syncthreads();

  const float e0 = __expf(v0 - mx);
  const float e1 = __expf(v1 - mx);
  red[t] = e0 + e1;
  __syncthreads();
  for (int s = 128; s > 0; s >>= 1) {
    if (t < s) red[t] += red[t + s];
    __syncthreads();
  }
  const float inv = 1.0f / red[0];

  prob[n * NN + t] = e0 * inv;
  prob[n * NN + 256 + t] = e1 * inv;
}

// ---------------------------------------------------------------------------
extern "C" void kernel_launch(void* const* d_in, const int* in_sizes, int n_in,
                              void* d_out, int out_size, void* d_ws, size_t ws_size,
                              hipStream_t stream) {
  (void)in_sizes; (void)n_in; (void)out_size; (void)ws_size;

  const float* x   = (const float*)d_in[0];  // (256, 512)
  const float* src = (const float*)d_in[1];  // (256, 512)
  const float* w1  = (const float*)d_in[2];  // (256, 512)
  const float* b1  = (const float*)d_in[3];  // (256,)
  const float* w2  = (const float*)d_in[4];  // (1, 256)
  const float* b2  = (const float*)d_in[5];  // (1,)
  const float* wa  = (const float*)d_in[6];  // (512, 512)
  const float* ba  = (const float*)d_in[7];  // (512,)
  const float* wb  = (const float*)d_in[8];  // (256, 512)
  const float* bb  = (const float*)d_in[9];  // (256,)

  float* y_out  = (float*)d_out;             // (256, 512)
  float* sc_out = (float*)d_out + 131072;    // (512, 512)

  // Workspace layout (floats). h2A/h2B overlay aq+ak / prob once consumed.
  float* ws = (float*)d_ws;
  float* aq   = ws;             // 131072   (dead after scores)
  float* ak   = ws + 131072;    // 131072   (dead after scores)
  float* prob = ws + 262144;    // 262144   (dead after msg)
  float* msgA = ws + 524288;    // 131072
  float* msgB = ws + 655360;    // 131072
  float* h2A  = ws;             // 262144   overlays aq+ak
  float* h2B  = ws + 262144;    // 262144   overlays prob

  aqak_kernel<<<dim3(8, 8, 2), 256, 0, stream>>>(w1, x, src, b1, aq, ak);
  scores_kernel<<<dim3(16, 16), 256, 0, stream>>>(aq, ak, w2, b2, sc_out);
  softmax_kernel<<<dim3(512), 256, 0, stream>>>(sc_out, prob);
  msg_kernel<<<dim3(8, 8, 2), 256, 0, stream>>>(src, prob, msgA, msgB);
  h2_kernel<<<dim3(8, 16, 2), 256, 0, stream>>>(wa, x, msgA, msgB, ba, h2A, h2B);
  y_kernel<<<dim3(8, 8), 256, 0, stream>>>(wb, h2A, h2B, bb, y_out);
}

// Round 3
// 117.504 us; speedup vs baseline: 5.1067x; 1.4163x over previous
//
#include <hip/hip_runtime.h>
#include <hip/hip_bf16.h>

#define DD 256
#define NN 512

typedef __attribute__((ext_vector_type(8))) short short8;
typedef __attribute__((ext_vector_type(4))) float floatx4;

// ---- f32 -> bf16 round-to-nearest-even (manual, no header dependency) ----
__device__ __forceinline__ unsigned short f2bf(float f) {
  unsigned u = __float_as_uint(f);
  u += 0x7FFFu + ((u >> 16) & 1u);
  return (unsigned short)(u >> 16);
}

// ---------------------------------------------------------------------------
// MFMA fragment loader. For mfma_f32_16x16x32_bf16:
//   A-frag: lane holds A[m = lane&15][k = (lane>>4)*8 + j], j=0..7
//   B-frag (from B^T stored [n][k], k contiguous): same pattern with n rows.
// Source is bf16 row-major [rows][ld], k contiguous -> one 16B load per lane.
// ---------------------------------------------------------------------------
__device__ __forceinline__ short8 ldfrag(const unsigned short* __restrict__ base,
                                         int row, int ld, int k, int lane) {
  const unsigned short* p = base + (row + (lane & 15)) * ld + k + ((lane >> 4) << 3);
  return *(const short8*)p;
}

// ---------------------------------------------------------------------------
// One-wave GEMM: C[m0..m0+16][n0..n0+64] += A(16 x K) * B_eff(K x 64)
// A bf16 [M][lda] (k contig), BT bf16 [N][ldb] (k contig, B_eff[k][n]=BT[n][k]).
// Epilogue: optional col-bias / row-bias / relu; f32 or bf16 output.
// ---------------------------------------------------------------------------
__device__ __forceinline__ void gemm_acc(floatx4 acc[4],
    const unsigned short* __restrict__ A, int lda,
    const unsigned short* __restrict__ BT, int ldb,
    int K, int a_k0, int b_k0, int m0, int n0, int lane) {
  for (int k = 0; k < K; k += 32) {
    short8 a = ldfrag(A, m0, lda, a_k0 + k, lane);
#pragma unroll
    for (int nf = 0; nf < 4; ++nf) {
      short8 b = ldfrag(BT, n0 + nf * 16, ldb, b_k0 + k, lane);
      acc[nf] = __builtin_amdgcn_mfma_f32_16x16x32_bf16(a, b, acc[nf], 0, 0, 0);
    }
  }
}

template <bool COLBIAS, bool ROWBIAS, bool RELU, bool OUTBF>
__device__ __forceinline__ void gemm_epi(floatx4 acc[4],
    const float* __restrict__ bias, void* __restrict__ C, int ldc,
    int m0, int n0, int lane) {
  const int col = lane & 15;
  const int q = lane >> 4;
#pragma unroll
  for (int nf = 0; nf < 4; ++nf) {
    const int n = n0 + nf * 16 + col;
    const float cb = COLBIAS ? bias[n] : 0.0f;
#pragma unroll
    for (int r = 0; r < 4; ++r) {
      const int m = m0 + q * 4 + r;
      float v = acc[nf][r] + cb + (ROWBIAS ? bias[m] : 0.0f);
      if (RELU) v = fmaxf(v, 0.0f);
      if (OUTBF) ((unsigned short*)C)[m * ldc + n] = f2bf(v);
      else       ((float*)C)[m * ldc + n] = v;
    }
  }
}

__device__ __forceinline__ void acc_zero(floatx4 acc[4]) {
#pragma unroll
  for (int i = 0; i < 4; ++i) {
    acc[i][0] = 0.f; acc[i][1] = 0.f; acc[i][2] = 0.f; acc[i][3] = 0.f;
  }
}

// ---------------------------------------------------------------------------
// prep: bf16 copies. blocks 0..639: flat cvt (w1 128 | wa 256 | wb 128 | src 128)
//       blocks 640..895: transpose+cvt x,src -> xT,srcT [n][d]
// ---------------------------------------------------------------------------
__global__ __launch_bounds__(256) void prep_kernel(
    const float* __restrict__ x, const float* __restrict__ src,
    const float* __restrict__ w1, const float* __restrict__ wa,
    const float* __restrict__ wb,
    unsigned short* __restrict__ w1b, unsigned short* __restrict__ wab,
    unsigned short* __restrict__ wbb, unsigned short* __restrict__ srcb,
    unsigned short* __restrict__ xT, unsigned short* __restrict__ srcT) {
  const int bid = blockIdx.x;
  const int tid = threadIdx.x;
  if (bid < 640) {
    const float* in; unsigned short* out; int off;
    if (bid < 128)      { in = w1;  out = w1b; off = bid; }
    else if (bid < 384) { in = wa;  out = wab; off = bid - 128; }
    else if (bid < 512) { in = wb;  out = wbb; off = bid - 384; }
    else                { in = src; out = srcb; off = bid - 512; }
    const int i = off * 1024 + tid * 4;
    const float4 v = *(const float4*)(in + i);
    const unsigned lo = (unsigned)f2bf(v.x) | ((unsigned)f2bf(v.y) << 16);
    const unsigned hi = (unsigned)f2bf(v.z) | ((unsigned)f2bf(v.w) << 16);
    *(uint2*)(out + i) = make_uint2(lo, hi);
  } else {
    __shared__ float tile[32][33];
    const int b = bid - 640;
    const float* in = (b >> 7) ? src : x;
    unsigned short* out = (b >> 7) ? srcT : xT;
    const int t = b & 127;
    const int n0 = (t >> 3) * 32;   // 16 n-tiles
    const int d0 = (t & 7) * 32;    // 8 d-tiles
    const int tx = tid & 31, ty = tid >> 5;
#pragma unroll
    for (int i = ty; i < 32; i += 8)
      tile[i][tx] = in[(d0 + i) * NN + n0 + tx];
    __syncthreads();
#pragma unroll
    for (int i = ty; i < 32; i += 8)
      out[(n0 + i) * DD + d0 + tx] = f2bf(tile[tx][i]);
  }
}

// ---- aqT[n][d] = sum_dd xT[n][dd] w1[d][dd] + b1[d] (z=0); akT (z=1) -------
__global__ __launch_bounds__(64) void aqak_kernel(
    const unsigned short* __restrict__ xT, const unsigned short* __restrict__ srcT,
    const unsigned short* __restrict__ w1b, const float* __restrict__ b1,
    float* __restrict__ aqT, float* __restrict__ akT) {
  const int lane = threadIdx.x;
  const int m0 = blockIdx.y * 16;   // n-index (0..511)
  const int n0 = blockIdx.x * 64;   // d-index (0..255)
  floatx4 acc[4]; acc_zero(acc);
  if (blockIdx.z == 0) {
    gemm_acc(acc, xT, 256, w1b, 512, 256, 0, 0, m0, n0, lane);
    gemm_epi<true, false, false, false>(acc, b1, aqT, 256, m0, n0, lane);
  } else {
    gemm_acc(acc, srcT, 256, w1b + 256, 512, 256, 0, 0, m0, n0, lane);
    gemm_epi<false, false, false, false>(acc, nullptr, akT, 256, m0, n0, lane);
  }
}

// ---- scores[n][m] = b2 + sum_d w2[d] relu(aqT[n][d] + akT[m][d]) ----------
// thread: m = bx*32 + (tid&31); n-rows n0t..n0t+3 = by*32 + (tid>>5)*4 ..
__global__ __launch_bounds__(256) void scores_kernel(
    const float* __restrict__ aqT, const float* __restrict__ akT,
    const float* __restrict__ w2, const float* __restrict__ b2,
    float* __restrict__ sc) {
  const int tid = threadIdx.x;
  const int m = blockIdx.x * 32 + (tid & 31);
  const int n0t = blockIdx.y * 32 + (tid >> 5) * 4;
  const float* akp = akT + m * DD;
  const float* aq0 = aqT + n0t * DD;
  float s0 = 0.f, s1 = 0.f, s2 = 0.f, s3 = 0.f;
  for (int d = 0; d < DD; d += 4) {
    const float4 w = *(const float4*)(w2 + d);
    const float4 kv = *(const float4*)(akp + d);
    const float4 a0 = *(const float4*)(aq0 + d);
    const float4 a1 = *(const float4*)(aq0 + DD + d);
    const float4 a2 = *(const float4*)(aq0 + 2 * DD + d);
    const float4 a3 = *(const float4*)(aq0 + 3 * DD + d);
    s0 += w.x * fmaxf(a0.x + kv.x, 0.f) + w.y * fmaxf(a0.y + kv.y, 0.f)
        + w.z * fmaxf(a0.z + kv.z, 0.f) + w.w * fmaxf(a0.w + kv.w, 0.f);
    s1 += w.x * fmaxf(a1.x + kv.x, 0.f) + w.y * fmaxf(a1.y + kv.y, 0.f)
        + w.z * fmaxf(a1.z + kv.z, 0.f) + w.w * fmaxf(a1.w + kv.w, 0.f);
    s2 += w.x * fmaxf(a2.x + kv.x, 0.f) + w.y * fmaxf(a2.y + kv.y, 0.f)
        + w.z * fmaxf(a2.z + kv.z, 0.f) + w.w * fmaxf(a2.w + kv.w, 0.f);
    s3 += w.x * fmaxf(a3.x + kv.x, 0.f) + w.y * fmaxf(a3.y + kv.y, 0.f)
        + w.z * fmaxf(a3.z + kv.z, 0.f) + w.w * fmaxf(a3.w + kv.w, 0.f);
  }
  const float bv = b2[0];
  sc[(n0t + 0) * NN + m] = s0 + bv;
  sc[(n0t + 1) * NN + m] = s1 + bv;
  sc[(n0t + 2) * NN + m] = s2 + bv;
  sc[(n0t + 3) * NN + m] = s3 + bv;
}

// ---- softmax over m; writes prob as bf16 [n][m] ---------------------------
__global__ __launch_bounds__(256) void softmax_kernel(
    const float* __restrict__ sc, unsigned short* __restrict__ probb) {
  __shared__ float red[256];
  const int n = blockIdx.x;
  const int t = threadIdx.x;
  const float v0 = sc[n * NN + t];
  const float v1 = sc[n * NN + 256 + t];
  red[t] = fmaxf(v0, v1);
  __syncthreads();
  for (int s = 128; s > 0; s >>= 1) {
    if (t < s) red[t] = fmaxf(red[t], red[t + s]);
    __syncthreads();
  }
  const float mx = red[0];
  __syncthreads();
  const float e0 = __expf(v0 - mx);
  const float e1 = __expf(v1 - mx);
  red[t] = e0 + e1;
  __syncthreads();
  for (int s = 128; s > 0; s >>= 1) {
    if (t < s) red[t] += red[t + s];
    __syncthreads();
  }
  const float inv = 1.0f / red[0];
  probb[n * NN + t]       = f2bf(e0 * inv);
  probb[n * NN + 256 + t] = f2bf(e1 * inv);
}

// ---- msgT[n][d] = sum_m prob[n][m] src[d][m] ------------------------------
__global__ __launch_bounds__(64) void msgT_kernel(
    const unsigned short* __restrict__ probb, const unsigned short* __restrict__ srcb,
    unsigned short* __restrict__ msgTb) {
  const int lane = threadIdx.x;
  const int m0 = blockIdx.y * 16;   // n
  const int n0 = blockIdx.x * 64;   // d
  floatx4 acc[4]; acc_zero(acc);
  gemm_acc(acc, probb, 512, srcb, 512, 512, 0, 0, m0, n0, lane);
  gemm_epi<false, false, false, true>(acc, nullptr, msgTb, 256, m0, n0, lane);
}

// ---- h2T[n][o] = relu( sum_c catT[n][c] wa[o][c] + ba[o] ), bf16 out ------
__global__ __launch_bounds__(64) void h2T_kernel(
    const unsigned short* __restrict__ xT, const unsigned short* __restrict__ msgTb,
    const unsigned short* __restrict__ wab, const float* __restrict__ ba,
    unsigned short* __restrict__ h2Tb) {
  const int lane = threadIdx.x;
  const int m0 = blockIdx.y * 16;   // n
  const int n0 = blockIdx.x * 64;   // o
  floatx4 acc[4]; acc_zero(acc);
  gemm_acc(acc, xT,    256, wab, 512, 256, 0, 0,   m0, n0, lane);  // c in [0,256)
  gemm_acc(acc, msgTb, 256, wab, 512, 256, 0, 256, m0, n0, lane);  // c in [256,512)
  gemm_epi<true, false, true, true>(acc, ba, h2Tb, 512, m0, n0, lane);
}

// ---- y[o][n] = sum_{o'} wb[o][o'] h2T[n][o'] + bb[o], f32 out -------------
__global__ __launch_bounds__(64) void y_kernel(
    const unsigned short* __restrict__ wbb, const unsigned short* __restrict__ h2Tb,
    const float* __restrict__ bb, float* __restrict__ y) {
  const int lane = threadIdx.x;
  const int m0 = blockIdx.y * 16;   // o
  const int n0 = blockIdx.x * 64;   // n
  floatx4 acc[4]; acc_zero(acc);
  gemm_acc(acc, wbb, 512, h2Tb, 512, 512, 0, 0, m0, n0, lane);
  gemm_epi<false, true, false, false>(acc, bb, y, 512, m0, n0, lane);
}

// ---------------------------------------------------------------------------
extern "C" void kernel_launch(void* const* d_in, const int* in_sizes, int n_in,
                              void* d_out, int out_size, void* d_ws, size_t ws_size,
                              hipStream_t stream) {
  (void)in_sizes; (void)n_in; (void)out_size; (void)ws_size;

  const float* x   = (const float*)d_in[0];
  const float* src = (const float*)d_in[1];
  const float* w1  = (const float*)d_in[2];
  const float* b1  = (const float*)d_in[3];
  const float* w2  = (const float*)d_in[4];
  const float* b2  = (const float*)d_in[5];
  const float* wa  = (const float*)d_in[6];
  const float* ba  = (const float*)d_in[7];
  const float* wb  = (const float*)d_in[8];
  const float* bb  = (const float*)d_in[9];

  float* y_out  = (float*)d_out;            // (256,512)
  float* sc_out = (float*)d_out + 131072;   // (512,512)

  char* ws = (char*)d_ws;
  unsigned short* w1b   = (unsigned short*)(ws);                 // 256KB
  unsigned short* wab   = (unsigned short*)(ws + (256 << 10));   // 512KB
  unsigned short* wbb   = (unsigned short*)(ws + (768 << 10));   // 256KB
  unsigned short* srcb  = (unsigned short*)(ws + (1024 << 10));  // 256KB
  unsigned short* xT    = (unsigned short*)(ws + (1280 << 10));  // 256KB
  unsigned short* srcT  = (unsigned short*)(ws + (1536 << 10));  // 256KB
  unsigned short* probb = (unsigned short*)(ws + (1792 << 10));  // 512KB
  unsigned short* msgTb = (unsigned short*)(ws + (2304 << 10));  // 256KB
  unsigned short* h2Tb  = (unsigned short*)(ws + (2560 << 10));  // 512KB
  float*          aqT   = (float*)(ws + (3072 << 10));           // 512KB
  float*          akT   = (float*)(ws + (3584 << 10));           // 512KB

  prep_kernel<<<896, 256, 0, stream>>>(x, src, w1, wa, wb,
                                       w1b, wab, wbb, srcb, xT, srcT);
  aqak_kernel<<<dim3(4, 32, 2), 64, 0, stream>>>(xT, srcT, w1b, b1, aqT, akT);
  scores_kernel<<<dim3(16, 16), 256, 0, stream>>>(aqT, akT, w2, b2, sc_out);
  softmax_kernel<<<512, 256, 0, stream>>>(sc_out, probb);
  msgT_kernel<<<dim3(4, 32), 64, 0, stream>>>(probb, srcb, msgTb);
  h2T_kernel<<<dim3(8, 32), 64, 0, stream>>>(xT, msgTb, wab, ba, h2Tb);
  y_kernel<<<dim3(8, 16), 64, 0, stream>>>(wbb, h2Tb, bb, y_out);
}

// Round 4
// 108.445 us; speedup vs baseline: 5.5333x; 1.0835x over previous
//
#include <hip/hip_runtime.h>
#include <hip/hip_bf16.h>

#define DD 256
#define NN 512

typedef __attribute__((ext_vector_type(8))) short short8;
typedef __attribute__((ext_vector_type(4))) float floatx4;

// ---- f32 -> bf16 round-to-nearest-even ----
__device__ __forceinline__ unsigned short f2bf(float f) {
  unsigned u = __float_as_uint(f);
  u += 0x7FFFu + ((u >> 16) & 1u);
  return (unsigned short)(u >> 16);
}
__device__ __forceinline__ unsigned pack2(float a, float b) {
  return (unsigned)f2bf(a) | ((unsigned)f2bf(b) << 16);
}

// ---------------------------------------------------------------------------
// MFMA fragment loader (global, bf16 rows with k contiguous):
// lane holds X[row = lane&15][k = k0 + (lane>>4)*8 + j], j=0..7 -> one 16B load
// ---------------------------------------------------------------------------
__device__ __forceinline__ short8 ldfrag(const unsigned short* __restrict__ base,
                                         int row, int ld, int k, int lane) {
  return *(const short8*)(base + (row + (lane & 15)) * ld + k + ((lane >> 4) << 3));
}

// One wave accumulates C[16 x 64] over K (multiple of 32).
__device__ __forceinline__ void gemm_acc(floatx4 acc[4],
    const unsigned short* __restrict__ A, int lda, int a_k0,
    const unsigned short* __restrict__ BT, int ldb, int b_k0,
    int K, int m0, int n0, int lane) {
  for (int k = 0; k < K; k += 32) {
    short8 a = ldfrag(A, m0, lda, a_k0 + k, lane);
#pragma unroll
    for (int nf = 0; nf < 4; ++nf) {
      short8 b = ldfrag(BT, n0 + nf * 16, ldb, b_k0 + k, lane);
      acc[nf] = __builtin_amdgcn_mfma_f32_16x16x32_bf16(a, b, acc[nf], 0, 0, 0);
    }
  }
}

__device__ __forceinline__ void acc_zero(floatx4 acc[4]) {
#pragma unroll
  for (int i = 0; i < 4; ++i) {
    acc[i][0] = 0.f; acc[i][1] = 0.f; acc[i][2] = 0.f; acc[i][3] = 0.f;
  }
}

// Split-K combine across 4 waves via LDS; wave 0 ends with the full sum.
// red = float[3*1024], layout [w-1][m(16)][n(64)] (n across lanes -> no conflict)
__device__ __forceinline__ void ksplit_combine(floatx4 acc[4], float* red,
                                               int wave, int lane) {
  const int col = lane & 15;
  const int q = lane >> 4;
  if (wave > 0) {
    float* base = red + (wave - 1) * 1024;
#pragma unroll
    for (int nf = 0; nf < 4; ++nf)
#pragma unroll
      for (int r = 0; r < 4; ++r)
        base[(q * 4 + r) * 64 + nf * 16 + col] = acc[nf][r];
  }
  __syncthreads();
  if (wave == 0) {
#pragma unroll
    for (int nf = 0; nf < 4; ++nf)
#pragma unroll
      for (int r = 0; r < 4; ++r) {
        const int idx = (q * 4 + r) * 64 + nf * 16 + col;
        acc[nf][r] += red[idx] + red[1024 + idx] + red[2048 + idx];
      }
  }
}

// Epilogue for the C-layout (col = lane&15, row = (lane>>4)*4 + r).
template <bool COLBIAS, bool ROWBIAS, bool RELU, bool OUTBF>
__device__ __forceinline__ void gemm_epi(floatx4 acc[4],
    const float* __restrict__ bias, void* __restrict__ C, int ldc,
    int m0, int n0, int lane) {
  const int col = lane & 15;
  const int q = lane >> 4;
#pragma unroll
  for (int nf = 0; nf < 4; ++nf) {
    const int n = n0 + nf * 16 + col;
    const float cb = COLBIAS ? bias[n] : 0.0f;
#pragma unroll
    for (int r = 0; r < 4; ++r) {
      const int m = m0 + q * 4 + r;
      float v = acc[nf][r] + cb + (ROWBIAS ? bias[m] : 0.0f);
      if (RELU) v = fmaxf(v, 0.0f);
      if (OUTBF) ((unsigned short*)C)[m * ldc + n] = f2bf(v);
      else       ((float*)C)[m * ldc + n] = v;
    }
  }
}

// ---------------------------------------------------------------------------
// prep: bf16 copies. blocks 0..639: flat cvt (w1 128 | wa 256 | wb 128 | src 128)
//       blocks 640..895: transpose+cvt x,src -> xT,srcT [n][d]
// ---------------------------------------------------------------------------
__global__ __launch_bounds__(256) void prep_kernel(
    const float* __restrict__ x, const float* __restrict__ src,
    const float* __restrict__ w1, const float* __restrict__ wa,
    const float* __restrict__ wb,
    unsigned short* __restrict__ w1b, unsigned short* __restrict__ wab,
    unsigned short* __restrict__ wbb, unsigned short* __restrict__ srcb,
    unsigned short* __restrict__ xT, unsigned short* __restrict__ srcT) {
  const int bid = blockIdx.x;
  const int tid = threadIdx.x;
  if (bid < 640) {
    const float* in; unsigned short* out; int off;
    if (bid < 128)      { in = w1;  out = w1b; off = bid; }
    else if (bid < 384) { in = wa;  out = wab; off = bid - 128; }
    else if (bid < 512) { in = wb;  out = wbb; off = bid - 384; }
    else                { in = src; out = srcb; off = bid - 512; }
    const int i = off * 1024 + tid * 4;
    const float4 v = *(const float4*)(in + i);
    *(uint2*)(out + i) = make_uint2(pack2(v.x, v.y), pack2(v.z, v.w));
  } else {
    __shared__ float tile[32][33];
    const int b = bid - 640;
    const float* in = (b >> 7) ? src : x;
    unsigned short* out = (b >> 7) ? srcT : xT;
    const int t = b & 127;
    const int n0 = (t >> 3) * 32;
    const int d0 = (t & 7) * 32;
    const int tx = tid & 31, ty = tid >> 5;
#pragma unroll
    for (int i = ty; i < 32; i += 8)
      tile[i][tx] = in[(d0 + i) * NN + n0 + tx];
    __syncthreads();
#pragma unroll
    for (int i = ty; i < 32; i += 8)
      out[(n0 + i) * DD + d0 + tx] = f2bf(tile[tx][i]);
  }
}

// ---- aq[d][n] (+b1[d]) / ak[d][n], f32 out. A = w1 rows (k contig), B^T = xT/srcT.
// grid (8 n-tiles, 16 d-tiles, 2), 256 threads = 4 waves, split-K/4.
__global__ __launch_bounds__(256) void aqak_kernel(
    const unsigned short* __restrict__ xT, const unsigned short* __restrict__ srcT,
    const unsigned short* __restrict__ w1b, const float* __restrict__ b1,
    float* __restrict__ aq, float* __restrict__ ak) {
  __shared__ float red[3072];
  const int tid = threadIdx.x;
  const int lane = tid & 63;
  const int wave = tid >> 6;
  const int m0 = blockIdx.y * 16;   // d
  const int n0 = blockIdx.x * 64;   // token
  const int z = blockIdx.z;
  const unsigned short* BT = z ? srcT : xT;

  floatx4 acc[4]; acc_zero(acc);
  gemm_acc(acc, w1b, NN, z * 256 + wave * 64, BT, DD, wave * 64, 64, m0, n0, lane);
  ksplit_combine(acc, red, wave, lane);
  if (wave == 0) {
    if (z == 0) gemm_epi<false, true, false, false>(acc, b1, aq, NN, m0, n0, lane);
    else        gemm_epi<false, false, false, false>(acc, nullptr, ak, NN, m0, n0, lane);
  }
}

// ---- scores[n][m] = b2 + sum_d w2[d] relu(aq[d][n] + ak[d][m]) -------------
// R1-proven LDS-tiled structure; aq/ak are [d][n] f32 (n contig -> coalesced).
__global__ __launch_bounds__(256) void scores_kernel(
    const float* __restrict__ aq, const float* __restrict__ ak,
    const float* __restrict__ w2, const float* __restrict__ b2,
    float* __restrict__ sc) {
  __shared__ float aqs[128][32];
  __shared__ float aks[128][32];
  __shared__ float w2s[DD];

  const int tid = threadIdx.x;
  const int n0 = blockIdx.x * 32;
  const int m0 = blockIdx.y * 32;
  const int tn = tid & 31;
  const int tm4 = (tid >> 5) * 4;

  w2s[tid] = w2[tid];

  float s0 = 0.f, s1 = 0.f, s2 = 0.f, s3 = 0.f;

  for (int d0 = 0; d0 < DD; d0 += 128) {
    __syncthreads();
#pragma unroll
    for (int k = 0; k < 16; ++k) {
      const int idx = k * 256 + tid;
      const int r = idx >> 5, cc = idx & 31;
      aqs[r][cc] = aq[(d0 + r) * NN + n0 + cc];
      aks[r][cc] = ak[(d0 + r) * NN + m0 + cc];
    }
    __syncthreads();

    for (int dd = 0; dd < 128; ++dd) {
      const float w = w2s[d0 + dd];
      const float a = aqs[dd][tn];
      const float4 akv = *(const float4*)&aks[dd][tm4];
      s0 += w * fmaxf(a + akv.x, 0.f);
      s1 += w * fmaxf(a + akv.y, 0.f);
      s2 += w * fmaxf(a + akv.z, 0.f);
      s3 += w * fmaxf(a + akv.w, 0.f);
    }
  }

  const float bv = b2[0];
  float4 o;
  o.x = s0 + bv; o.y = s1 + bv; o.z = s2 + bv; o.w = s3 + bv;
  *(float4*)&sc[(n0 + tn) * NN + m0 + tm4] = o;
}

// ---- msgT: softmax (rows n0..n0+15 of sc) fused with P @ src^T --------------
// msgT[n][d] = sum_m softmax(sc)[n][m] * src[d][m], bf16 out.
// grid (4 d-tiles, 32 n-tiles), 256 threads; P-tile bf16 in LDS; split-K/4 over m.
__global__ __launch_bounds__(256) void msgT_kernel(
    const float* __restrict__ sc, const unsigned short* __restrict__ srcb,
    unsigned short* __restrict__ msgTb) {
  __shared__ unsigned short Ap[16][520];   // [row][m], +8 pad (16B-aligned rows)
  __shared__ float red[3072];
  __shared__ float smax[16][16];
  __shared__ float ssum[16][16];
  __shared__ float rst[16][2];             // [row][{max,sum}]

  const int tid = threadIdx.x;
  const int lane = tid & 63;
  const int wave = tid >> 6;
  const int n0 = blockIdx.y * 16;   // token rows
  const int d0 = blockIdx.x * 64;   // d tile

  // ---------- softmax phase ----------
  const int r = tid >> 4;      // 0..15
  const int seg = tid & 15;    // 32 m's each
  float4 v[8];
  const float* rp = sc + (n0 + r) * NN + seg * 32;
#pragma unroll
  for (int i = 0; i < 8; ++i) v[i] = *(const float4*)(rp + i * 4);

  float mx = -3.0e38f;
#pragma unroll
  for (int i = 0; i < 8; ++i)
    mx = fmaxf(mx, fmaxf(fmaxf(v[i].x, v[i].y), fmaxf(v[i].z, v[i].w)));
  smax[r][seg] = mx;
  __syncthreads();
  if (seg == 0) {
    float m2 = smax[r][0];
#pragma unroll
    for (int i = 1; i < 16; ++i) m2 = fmaxf(m2, smax[r][i]);
    rst[r][0] = m2;
  }
  __syncthreads();
  mx = rst[r][0];

  float sum = 0.f;
#pragma unroll
  for (int i = 0; i < 8; ++i) {
    v[i].x = __expf(v[i].x - mx); v[i].y = __expf(v[i].y - mx);
    v[i].z = __expf(v[i].z - mx); v[i].w = __expf(v[i].w - mx);
    sum += v[i].x + v[i].y + v[i].z + v[i].w;
  }
  ssum[r][seg] = sum;
  __syncthreads();
  if (seg == 0) {
    float s2 = ssum[r][0];
#pragma unroll
    for (int i = 1; i < 16; ++i) s2 += ssum[r][i];
    rst[r][1] = s2;
  }
  __syncthreads();
  const float inv = 1.0f / rst[r][1];
#pragma unroll
  for (int i = 0; i < 8; ++i) {
    *(unsigned*)&Ap[r][seg * 32 + i * 4]     = pack2(v[i].x * inv, v[i].y * inv);
    *(unsigned*)&Ap[r][seg * 32 + i * 4 + 2] = pack2(v[i].z * inv, v[i].w * inv);
  }
  __syncthreads();

  // ---------- GEMM phase (A from LDS, split-K over m) ----------
  floatx4 acc[4]; acc_zero(acc);
  const int k0w = wave * 128;
  const int arow = lane & 15;
  const int koff = (lane >> 4) << 3;
  for (int k = 0; k < 128; k += 32) {
    short8 a = *(const short8*)&Ap[arow][k0w + k + koff];
#pragma unroll
    for (int nf = 0; nf < 4; ++nf) {
      short8 b = ldfrag(srcb, d0 + nf * 16, NN, k0w + k, lane);
      acc[nf] = __builtin_amdgcn_mfma_f32_16x16x32_bf16(a, b, acc[nf], 0, 0, 0);
    }
  }
  ksplit_combine(acc, red, wave, lane);
  if (wave == 0)
    gemm_epi<false, false, false, true>(acc, nullptr, msgTb, DD, n0, d0, lane);
}

// ---- h2T[n][o] = relu(xT@waL^T + msgT@waR^T + ba[o]), bf16; split-K/4 ------
__global__ __launch_bounds__(256) void h2T_kernel(
    const unsigned short* __restrict__ xT, const unsigned short* __restrict__ msgTb,
    const unsigned short* __restrict__ wab, const float* __restrict__ ba,
    unsigned short* __restrict__ h2Tb) {
  __shared__ float red[3072];
  const int tid = threadIdx.x;
  const int lane = tid & 63;
  const int wave = tid >> 6;
  const int m0 = blockIdx.y * 16;   // token
  const int n0 = blockIdx.x * 64;   // o

  floatx4 acc[4]; acc_zero(acc);
  const unsigned short* A = (wave < 2) ? xT : msgTb;
  gemm_acc(acc, A, DD, (wave & 1) * 128, wab, NN, wave * 128, 128, m0, n0, lane);
  ksplit_combine(acc, red, wave, lane);
  if (wave == 0)
    gemm_epi<true, false, true, true>(acc, ba, h2Tb, NN, m0, n0, lane);
}

// ---- y[o][n] = wb @ relu-h2 + bb[o], f32 out; split-K/4 --------------------
__global__ __launch_bounds__(256) void y_kernel(
    const unsigned short* __restrict__ wbb, const unsigned short* __restrict__ h2Tb,
    const float* __restrict__ bb, float* __restrict__ y) {
  __shared__ float red[3072];
  const int tid = threadIdx.x;
  const int lane = tid & 63;
  const int wave = tid >> 6;
  const int m0 = blockIdx.y * 16;   // o
  const int n0 = blockIdx.x * 64;   // token

  floatx4 acc[4]; acc_zero(acc);
  gemm_acc(acc, wbb, NN, wave * 128, h2Tb, NN, wave * 128, 128, m0, n0, lane);
  ksplit_combine(acc, red, wave, lane);
  if (wave == 0)
    gemm_epi<false, true, false, false>(acc, bb, y, NN, m0, n0, lane);
}

// ---------------------------------------------------------------------------
extern "C" void kernel_launch(void* const* d_in, const int* in_sizes, int n_in,
                              void* d_out, int out_size, void* d_ws, size_t ws_size,
                              hipStream_t stream) {
  (void)in_sizes; (void)n_in; (void)out_size; (void)ws_size;

  const float* x   = (const float*)d_in[0];
  const float* src = (const float*)d_in[1];
  const float* w1  = (const float*)d_in[2];
  const float* b1  = (const float*)d_in[3];
  const float* w2  = (const float*)d_in[4];
  const float* b2  = (const float*)d_in[5];
  const float* wa  = (const float*)d_in[6];
  const float* ba  = (const float*)d_in[7];
  const float* wb  = (const float*)d_in[8];
  const float* bb  = (const float*)d_in[9];

  float* y_out  = (float*)d_out;            // (256,512)
  float* sc_out = (float*)d_out + 131072;   // (512,512)

  char* ws = (char*)d_ws;
  unsigned short* w1b   = (unsigned short*)(ws);                 // 256KB
  unsigned short* wab   = (unsigned short*)(ws + (256 << 10));   // 512KB
  unsigned short* wbb   = (unsigned short*)(ws + (768 << 10));   // 256KB
  unsigned short* srcb  = (unsigned short*)(ws + (1024 << 10));  // 256KB
  unsigned short* xT    = (unsigned short*)(ws + (1280 << 10));  // 256KB
  unsigned short* srcT  = (unsigned short*)(ws + (1536 << 10));  // 256KB
  unsigned short* msgTb = (unsigned short*)(ws + (1792 << 10));  // 256KB
  unsigned short* h2Tb  = (unsigned short*)(ws + (2048 << 10));  // 512KB
  float*          aq    = (float*)(ws + (2560 << 10));           // 512KB
  float*          ak    = (float*)(ws + (3072 << 10));           // 512KB

  prep_kernel<<<896, 256, 0, stream>>>(x, src, w1, wa, wb,
                                       w1b, wab, wbb, srcb, xT, srcT);
  aqak_kernel<<<dim3(8, 16, 2), 256, 0, stream>>>(xT, srcT, w1b, b1, aq, ak);
  scores_kernel<<<dim3(16, 16), 256, 0, stream>>>(aq, ak, w2, b2, sc_out);
  msgT_kernel<<<dim3(4, 32), 256, 0, stream>>>(sc_out, srcb, msgTb);
  h2T_kernel<<<dim3(8, 32), 256, 0, stream>>>(xT, msgTb, wab, ba, h2Tb);
  y_kernel<<<dim3(8, 16), 256, 0, stream>>>(wbb, h2Tb, bb, y_out);
}